// Round 6
// baseline (279.807 us; speedup 1.0000x reference)
//
#include <hip/hip_runtime.h>
#include <math.h>

typedef unsigned short ushort_t;
typedef __bf16 bf16x8 __attribute__((ext_vector_type(8)));
typedef ushort_t ushort8v __attribute__((ext_vector_type(8)));
typedef float f32x4 __attribute__((ext_vector_type(4)));

#define B_SZ   4
#define SEQ    8192
#define M_ROWS (B_SZ * SEQ)   // 32768
#define CH     128
#define NC     (SEQ / CH)     // 64

__device__ __forceinline__ ushort_t f2bf(float f) {
    unsigned u = __float_as_uint(f);
    u = u + 0x7fffu + ((u >> 16) & 1u);
    return (ushort_t)(u >> 16);
}
__device__ __forceinline__ float bf2f(ushort_t b) {
    return __uint_as_float(((unsigned)b) << 16);
}

__device__ __forceinline__ void load16_lds(const void* g, void* l) {
    __builtin_amdgcn_global_load_lds(
        (const __attribute__((address_space(1))) unsigned int*)g,
        (__attribute__((address_space(3))) unsigned int*)l, 16, 0, 0);
}

__device__ __forceinline__ bf16x8 ldfrag(const ushort_t* p) {
    union { ushort8v u; bf16x8 b; } cv;
    cv.u = *(const ushort8v*)p;
    return cv.b;
}

__device__ __forceinline__ float2 cmul(float2 a, float2 b) {
    return make_float2(a.x * b.x - a.y * b.y, a.x * b.y + a.y * b.x);
}

// ---------------------------------------------------------------------------
// prepconv: conv_x (all blocks) + prep (blocks < 1024).  PW now [q][8] =
// {a, a^4, a^16, a^64} complex for the fused carry.
__global__ void prepconv_kernel(const float* __restrict__ x,
                                ushort_t* __restrict__ X16,
                                const float* __restrict__ Lre,
                                const float* __restrict__ Lim,
                                const float* __restrict__ ldt,
                                const float* __restrict__ Bre,
                                const float* __restrict__ Bim,
                                const float* __restrict__ Cre,
                                const float* __restrict__ Cim,
                                float* __restrict__ abar,
                                float* __restrict__ apow,
                                float* __restrict__ PW,
                                ushort_t* __restrict__ Bmat,
                                ushort_t* __restrict__ Cmat) {
    int i = blockIdx.x * 256 + threadIdx.x;
    float4 v = ((const float4*)x)[i];
    ushort_t o[4] = {f2bf(v.x), f2bf(v.y), f2bf(v.z), f2bf(v.w)};
    *(uint2*)&X16[(size_t)i * 4] = *(const uint2*)o;

    if (blockIdx.x < 1024) {
        int idx = i;                        // 0 .. 262143
        int h = idx & 511;
        int p = (idx >> 9) & 255;
        int d = idx >> 17;
        int ip = d * 256 + p;
        float lr = Lre[ip], li = Lim[ip];
        float dt = expf(ldt[ip]);
        float e   = expf(lr * dt);
        float ang = li * dt;
        float ar = e * cosf(ang), ai = e * sinf(ang);
        float nr = ar - 1.0f, ni = ai;
        float den = lr * lr + li * li;
        float cr = (nr * lr + ni * li) / den;
        float ci = (ni * lr - nr * li) / den;
        float br = Bre[idx], bi = Bim[idx];
        Bmat[(d * 512 + 2 * p) * 512 + h]     = f2bf(cr * br - ci * bi);
        Bmat[(d * 512 + 2 * p + 1) * 512 + h] = f2bf(cr * bi + ci * br);
        if (h == 0) {
            int oo = d * 512 + 2 * p;
            abar[oo] = ar;  abar[oo + 1] = ai;
            float eC = expf(lr * dt * (float)CH);
            float aC = ang * (float)CH;
            apow[oo] = eC * cosf(aC);  apow[oo + 1] = eC * sinf(aC);
            float2 a1 = make_float2(ar, ai);
            float2 a2 = cmul(a1, a1);
            float2 a4 = cmul(a2, a2);
            float2 a8 = cmul(a4, a4);
            float2 a16 = cmul(a8, a8);
            float2 a32 = cmul(a16, a16);
            float2 a64 = cmul(a32, a32);
            int q = d * 256 + p;
            PW[q * 8 + 0] = a1.x;  PW[q * 8 + 1] = a1.y;
            PW[q * 8 + 2] = a4.x;  PW[q * 8 + 3] = a4.y;
            PW[q * 8 + 4] = a16.x; PW[q * 8 + 5] = a16.y;
            PW[q * 8 + 6] = a64.x; PW[q * 8 + 7] = a64.y;
        }
        int p2 = idx & 255;
        int h2 = (idx >> 8) & 511;
        int d2 = idx >> 17;
        Cmat[h2 * 1024 + d2 * 512 + 2 * p2]     = f2bf(Cre[idx]);
        Cmat[h2 * 1024 + d2 * 512 + 2 * p2 + 1] = f2bf(-Cim[idx]);
    }
}

// ---------------------------------------------------------------------------
// 128x256 bf16 MFMA GEMM, BK=32 double-buffered, 512 thr = 8 waves (2M x 4N),
// per-wave 64x64 -> acc[4][4] (64 regs/lane; total ~96+misc <= 128 with
// __launch_bounds__(512,4) => 2 blocks/CU = 16 waves/CU, LDS 48KB).
// Per K-tile: {8 ds_read frags; barrier; STAGE(t+2)->buf (3 loads);
// setprio(1); 16 MFMA; setprio(0); vmcnt(3) [never 0 mid-loop]; barrier}.
// Stage targets the slot whose reads were all ISSUED before the barrier; its
// DMA data returns >=200cyc later (L2), long after those reads drain (<120cy).
// Fused carry (EPI==0): block rows = exactly one 128-row chunk.  Per wave:
// S_wr = sum_j a^(dir? j : 63-j) * bu_j over its 64 rows (j = mi*16+lq*4+r,
// 4 CSTEPs with A16 powers).  Chunk carry: dir0 = A64*S_0 + S_1,
// dir1 = S_0 + A64*S_1 (wr0 waves finalize via 2KB LDS partial exchange).
template<int EPI, int KD_, int NT>
__global__ __launch_bounds__(512, 4)
void gemm_bk32(const ushort_t* __restrict__ A, const ushort_t* __restrict__ Bm,
               ushort_t* __restrict__ Cb, float* __restrict__ Cf,
               const float* __restrict__ X, const float* __restrict__ Dv,
               const float* __restrict__ PW, float* __restrict__ CAR) {
    __shared__ char smem[49152];
    ushort_t (*shA)[4096] = (ushort_t(*)[4096])smem;            // [2][128*32]
    ushort_t (*shB)[8192] = (ushort_t(*)[8192])(smem + 16384);  // [2][256*32]
    constexpr int NKT = KD_ / 32;

    const int tid  = threadIdx.x;
    const int lane = tid & 63;
    const int wv   = tid >> 6;
    const int wr = wv >> 2, wc = wv & 3;       // wr 0..1, wc 0..3
    const int l15 = lane & 15, lq = lane >> 4;

    // XCD swizzle: all NT n-tiles of an m-tile adjacent on one XCD.
    const int lin = blockIdx.x;
    const int xcd = lin & 7;
    const int j   = lin >> 3;
    const int mt  = xcd * 32 + j / NT;         // 256 m-tiles of 128 rows
    const int nt  = j % NT;
    const int m0 = mt * 128;
    const int n0 = nt * 256;
    const int CN = NT * 256;

    f32x4 acc[4][4];
#pragma unroll
    for (int i = 0; i < 4; ++i)
#pragma unroll
        for (int jj = 0; jj < 4; ++jj)
            acc[i][jj] = (f32x4){0.f, 0.f, 0.f, 0.f};

    // staging maps (LDS dest linear = base + lane*16B; global pre-swizzled)
    const int srA = wv * 16 + (lane >> 2);     // A: 8 waves x 16 rows = 128
    const int srB = wv * 32 + (lane >> 2);     // B: 2 insts x 16 rows
    const int sck = (((lane & 3) ^ ((lane >> 3) & 3))) * 8;
    const ushort_t* Ag = A  + (size_t)(m0 + srA) * KD_ + sck;
    const ushort_t* Bg = Bm + (size_t)(n0 + srB) * KD_ + sck;

#define STAGE(t) do {                                                         \
        load16_lds(Ag + (size_t)(t) * 32, &shA[(t) & 1][wv * 512]);           \
        load16_lds(Bg + (size_t)(t) * 32, &shB[(t) & 1][wv * 1024]);          \
        load16_lds(Bg + (size_t)(t) * 32 + (size_t)16 * KD_,                  \
                   &shB[(t) & 1][wv * 1024 + 512]);                           \
    } while (0)

    const int rdoff = ((lq ^ ((l15 >> 1) & 3))) * 8;
    const int rdA = (wr * 64 + l15) * 32 + rdoff;
    const int rdB = (wc * 64 + l15) * 32 + rdoff;

    STAGE(0); STAGE(1);
    asm volatile("s_waitcnt vmcnt(3)" ::: "memory");
    __builtin_amdgcn_s_barrier();

#pragma unroll 2
    for (int kt = 0; kt < NKT; ++kt) {
        const int buf = kt & 1;
        bf16x8 af[4], bq[4];
#pragma unroll
        for (int mi = 0; mi < 4; ++mi)
            af[mi] = ldfrag(&shA[buf][rdA + mi * 512]);
#pragma unroll
        for (int ni = 0; ni < 4; ++ni)
            bq[ni] = ldfrag(&shB[buf][rdB + ni * 512]);
        __builtin_amdgcn_s_barrier();
        if (kt + 2 < NKT) STAGE(kt + 2);
        __builtin_amdgcn_s_setprio(1);
#pragma unroll
        for (int mi = 0; mi < 4; ++mi)
#pragma unroll
            for (int ni = 0; ni < 4; ++ni)
                acc[mi][ni] = __builtin_amdgcn_mfma_f32_16x16x32_bf16(
                    af[mi], bq[ni], acc[mi][ni], 0, 0, 0);
        __builtin_amdgcn_s_setprio(0);
        if (kt + 1 < NKT) {
            if (kt + 2 < NKT)
                asm volatile("s_waitcnt vmcnt(3)" ::: "memory");
            else
                asm volatile("s_waitcnt vmcnt(0)" ::: "memory");
            __builtin_amdgcn_s_barrier();
        }
    }
#undef STAGE

    // ---- make smem safe to reuse as epilogue scratch ----
    asm volatile("s_waitcnt lgkmcnt(0)" ::: "memory");
    __builtin_amdgcn_s_barrier();

    const int rr = lane >> 2;            // store row within 16
    const int cc = (lane & 3) * 16;      // store col chunk (16 cols)

    if (EPI == 0) {
        // bf16 patch [16][72] (144B stride); 8 waves x 2304B = 18.4KB
        ushort_t* ep = (ushort_t*)(smem + wv * 2304);
#pragma unroll
        for (int mi = 0; mi < 4; ++mi) {
#pragma unroll
            for (int ni = 0; ni < 4; ++ni)
#pragma unroll
                for (int r = 0; r < 4; ++r)
                    ep[(lq * 4 + r) * 72 + ni * 16 + l15] = f2bf(acc[mi][ni][r]);
            uint4 w0 = *(const uint4*)&ep[rr * 72 + cc];
            uint4 w1 = *(const uint4*)&ep[rr * 72 + cc + 8];
            const int rowg = m0 + wr * 64 + mi * 16 + rr;
            *(uint4*)&Cb[(size_t)rowg * CN + n0 + wc * 64 + cc]     = w0;
            *(uint4*)&Cb[(size_t)rowg * CN + n0 + wc * 64 + cc + 8] = w1;
        }
    } else {
        // f32 patch [16][68] (272B stride); 8 waves x 4352B = 34.8KB
        float* epf = (float*)(smem + wv * 4352);
        const int colbase = n0 + wc * 64 + cc;
        f32x4 dsv[4];
#pragma unroll
        for (int j4 = 0; j4 < 4; ++j4)
            dsv[j4] = *(const f32x4*)&Dv[colbase + j4 * 4]
                    + *(const f32x4*)&Dv[512 + colbase + j4 * 4];
#pragma unroll
        for (int mi = 0; mi < 4; ++mi) {
#pragma unroll
            for (int ni = 0; ni < 4; ++ni)
#pragma unroll
                for (int r = 0; r < 4; ++r)
                    epf[(lq * 4 + r) * 68 + ni * 16 + l15] = acc[mi][ni][r];
            const int rowg = m0 + wr * 64 + mi * 16 + rr;
            const size_t gb = (size_t)rowg * 512 + colbase;
#pragma unroll
            for (int j4 = 0; j4 < 4; ++j4) {
                f32x4 v  = *(const f32x4*)&epf[rr * 68 + cc + j4 * 4];
                f32x4 xv = *(const f32x4*)&X[gb + j4 * 4];
                v = v + xv * dsv[j4];
                *(f32x4*)&Cf[gb + j4 * 4] = v;
            }
        }
    }

    // ---- fused chunk-carry (EPI==0): per-wave 64-row partial + A64 combine
    if (EPI == 0) {
        float* PLDS = (float*)(smem + 20480);        // [2][256] floats, 2KB
        const int dirq = ((n0 + wc * 64) >> 9) & 1;  // wave-uniform
        const bool evn = ((l15 & 1) == 0);
        float csA[4], cpA[4], a64x[4], a64y[4];

#define CACC(MI, R, CCo) do {                                                 \
            float vo = bf2f(f2bf(acc[MI][ni][R]));                            \
            float vp = __shfl_xor(vo, 1);                                     \
            float vr = evn ? vo : vp;                                         \
            float vi = evn ? vp : vo;                                         \
            wr_ = fmaf(CCo.x, vr, fmaf(-CCo.y, vi, wr_));                     \
            wi_ = fmaf(CCo.x, vi, fmaf(CCo.y, vr, wi_));                      \
        } while (0)
#define CSTEP(MI) do {                                                        \
            float wr_ = 0.f, wi_ = 0.f;                                       \
            CACC(MI, 0, c0); CACC(MI, 1, c1);                                 \
            CACC(MI, 2, c2); CACC(MI, 3, c3);                                 \
            float comp = evn ? (t16.x * wr_ - t16.y * wi_)                    \
                             : (t16.x * wi_ + t16.y * wr_);                   \
            csum += comp;                                                     \
            t16 = cmul(t16, A16);                                             \
        } while (0)

#pragma unroll
        for (int ni = 0; ni < 4; ++ni) {
            const int col = n0 + wc * 64 + ni * 16 + l15;
            const int q = col >> 1;
            float2 A1  = make_float2(PW[q * 8 + 0], PW[q * 8 + 1]);
            float2 A4  = make_float2(PW[q * 8 + 2], PW[q * 8 + 3]);
            float2 A16 = make_float2(PW[q * 8 + 4], PW[q * 8 + 5]);
            a64x[ni] = PW[q * 8 + 6]; a64y[ni] = PW[q * 8 + 7];
            const int lqp = dirq ? lq : 3 - lq;
            float2 A4_2 = cmul(A4, A4);
            float2 A4_3 = cmul(A4_2, A4);
            float2 P4 = (lqp == 0) ? make_float2(1.f, 0.f)
                       : (lqp == 1) ? A4
                       : (lqp == 2) ? A4_2 : A4_3;
            float2 c0, c1, c2, c3;
            if (dirq == 0) {
                c3 = P4; c2 = cmul(c3, A1); c1 = cmul(c2, A1); c0 = cmul(c1, A1);
            } else {
                c0 = P4; c1 = cmul(c0, A1); c2 = cmul(c1, A1); c3 = cmul(c2, A1);
            }
            float2 t16 = make_float2(1.f, 0.f);
            float csum = 0.f;
            if (dirq == 0) { CSTEP(3); CSTEP(2); CSTEP(1); CSTEP(0); }
            else           { CSTEP(0); CSTEP(1); CSTEP(2); CSTEP(3); }
            csum += __shfl_xor(csum, 16);
            csum += __shfl_xor(csum, 32);
            csA[ni] = csum;
            cpA[ni] = __shfl_xor(csum, 1);
            if (lq == 0)
                PLDS[wr * 256 + wc * 64 + ni * 16 + l15] = csum;
        }
        __builtin_amdgcn_s_barrier();
        if (wr == 0) {
#pragma unroll
            for (int ni = 0; ni < 4; ++ni) {
                const int cl = wc * 64 + ni * 16 + l15;
                float oth_same = PLDS[256 + cl];
                float oth_part = PLDS[256 + (cl ^ 1)];
                float own_re = evn ? csA[ni] : cpA[ni];
                float own_im = evn ? cpA[ni] : csA[ni];
                float oth_re = evn ? oth_same : oth_part;
                float oth_im = evn ? oth_part : oth_same;
                float Xre = dirq ? oth_re : own_re;
                float Xim = dirq ? oth_im : own_im;
                float Ysm = dirq ? csA[ni] : oth_same;
                float out = evn
                    ? fmaf(a64x[ni], Xre, fmaf(-a64y[ni], Xim, Ysm))
                    : fmaf(a64x[ni], Xim, fmaf( a64y[ni], Xre, Ysm));
                if (lq == 0)
                    CAR[(size_t)(m0 >> 7) * 1024 + n0 + cl] = out;
            }
        }
#undef CACC
#undef CSTEP
    }
}

// ---------------------------------------------------------------------------
// scan_fin2 = scan_comb folded into scan_final (unchanged).
__global__ __launch_bounds__(512)
void scan_fin2(ushort_t* __restrict__ S, const float* __restrict__ abar,
               const float* __restrict__ apow, const float* __restrict__ carry) {
    int b = blockIdx.x, c = blockIdx.y, t = threadIdx.x;
    int dir = t >> 8, p = t & 255;
    float ar = abar[dir * 512 + 2 * p], ai = abar[dir * 512 + 2 * p + 1];
    float pr = apow[dir * 512 + 2 * p], pi = apow[dir * 512 + 2 * p + 1];
    float sr = 0.f, si = 0.f;
    if (dir == 0) {
        for (int cc = 0; cc < c; ++cc) {
            int o = (b * NC + cc) * 1024 + 2 * p;
            float cr0 = carry[o], ci0 = carry[o + 1];
            float nr = fmaf(pr, sr, fmaf(-pi, si, cr0));
            float ni = fmaf(pr, si, fmaf(pi, sr, ci0));
            sr = nr; si = ni;
        }
    } else {
        for (int cc = NC - 1; cc > c; --cc) {
            int o = (b * NC + cc) * 1024 + 512 + 2 * p;
            float cr0 = carry[o], ci0 = carry[o + 1];
            float nr = fmaf(pr, sr, fmaf(-pi, si, cr0));
            float ni = fmaf(pr, si, fmaf(pi, sr, ci0));
            sr = nr; si = ni;
        }
    }
    ushort_t* base = S + ((size_t)b * SEQ + (size_t)c * CH) * 1024
                       + dir * 512 + 2 * p;
    for (int ii = 0; ii < CH; ++ii) {
        int i = dir ? (CH - 1 - ii) : ii;
        unsigned* addr = (unsigned*)(base + (size_t)i * 1024);
        unsigned u = *addr;
        float re = bf2f((ushort_t)(u & 0xffffu));
        float im = bf2f((ushort_t)(u >> 16));
        float nr = fmaf(ar, sr, fmaf(-ai, si, re));
        float ni = fmaf(ar, si, fmaf(ai, sr, im));
        sr = nr; si = ni;
        *addr = ((unsigned)f2bf(si) << 16) | (unsigned)f2bf(sr);
    }
}

// ---------------------------------------------------------------------------
// ws layout (bytes):
//  SB16 : 0           (67,108,864)  [M][1024] bf16 states both dirs
//  X16  : 67,108,864  (33,554,432)  bf16 x   (live through ALL of GEMM1)
//  Bm16 : 100,663,296 (1,048,576)
//  Cm16 : 101,711,872 (1,048,576)
//  abar : 102,760,448 (4,096)
//  apow : 102,764,544 (4,096)
// d_out scratch (dead until GEMM2 writes y; stream-ordered):
//  carry: d_out + 0         (1,048,576)
//  PW   : d_out + 1,048,576 (16,384)
extern "C" void kernel_launch(void* const* d_in, const int* in_sizes, int n_in,
                              void* d_out, int out_size, void* d_ws, size_t ws_size,
                              hipStream_t stream) {
    const float* x   = (const float*)d_in[0];
    const float* Lre = (const float*)d_in[1];
    const float* Lim = (const float*)d_in[2];
    const float* ldt = (const float*)d_in[3];
    const float* Bre = (const float*)d_in[4];
    const float* Bim = (const float*)d_in[5];
    const float* Cre = (const float*)d_in[6];
    const float* Cim = (const float*)d_in[7];
    const float* Dv  = (const float*)d_in[8];
    float* y = (float*)d_out;
    char* ws = (char*)d_ws;

    ushort_t* SB16 = (ushort_t*)(ws);
    ushort_t* X16  = (ushort_t*)(ws + 67108864);
    ushort_t* Bm16 = (ushort_t*)(ws + 100663296);
    ushort_t* Cm16 = (ushort_t*)(ws + 101711872);
    float* abar  = (float*)(ws + 102760448);
    float* apow  = (float*)(ws + 102764544);
    float* carry = (float*)d_out;                       // dead until GEMM2
    float* PW    = (float*)((char*)d_out + 1048576);    // dead until GEMM2

    prepconv_kernel<<<16384, 256, 0, stream>>>(x, X16, Lre, Lim, ldt,
                                               Bre, Bim, Cre, Cim,
                                               abar, apow, PW, Bm16, Cm16);

    // GEMM1: SB[M][1024] = X16[M][512] * Bm16[1024][512]^T  (+ fused carry)
    // 256 m-tiles x 4 n-tiles = 1024 blocks, 2 blocks/CU.
    gemm_bk32<0, 512, 4><<<1024, 512, 0, stream>>>(X16, Bm16, SB16, nullptr,
                                                   nullptr, nullptr, PW, carry);

    dim3 gs(B_SZ, NC);
    scan_fin2<<<gs, 512, 0, stream>>>(SB16, abar, apow, carry);

    // GEMM2: y[M][512] = SB16[M][1024] * Cm16[512][1024]^T + x*(D0+D1)
    // 256 m-tiles x 2 n-tiles = 512 blocks, 2 blocks/CU.
    gemm_bk32<1, 1024, 2><<<512, 512, 0, stream>>>(SB16, Cm16, nullptr, y,
                                                   x, Dv, nullptr, nullptr);
}